// Round 2
// baseline (414.998 us; speedup 1.0000x reference)
//
#include <hip/hip_runtime.h>

// NoisyTopKRouter: x[4,4096,4096] f32, W[4096,8] f32, b[8] f32, noise[16384,8] f32
// out: top_k_weights [16384*2] | top_k_indices [16384*2] (as float) | aux_loss [1]
// Memory-bound: must stream 256 MiB of x once. Floor ~43 us @ 6.3 TB/s.

#define BS      16384
#define HDIM    4096
#define NE      8
#define RPW     4        // rows per wave
#define WPB     4        // waves per block
#define NOISE_EPS 0.01f
#define LB_COEFF  0.01f

__global__ __launch_bounds__(256, 4)
void router_main(const float* __restrict__ x, const float* __restrict__ W,
                 const float* __restrict__ bias, const float* __restrict__ noise,
                 float* __restrict__ out, float* __restrict__ usage_ws) {
    const int tid  = threadIdx.x;
    const int lane = tid & 63;
    const int wave = tid >> 6;
    const int group = blockIdx.x * WPB + wave;      // 0..4095
    const int row0  = group * RPW;

    __shared__ float block_usage[NE];
    if (tid < NE) block_usage[tid] = 0.0f;
    __syncthreads();

    // ---- GEMM partials: acc[r][e] over this lane's h-subset ----
    float acc[RPW][NE];
#pragma unroll
    for (int r = 0; r < RPW; ++r)
#pragma unroll
        for (int e = 0; e < NE; ++e) acc[r][e] = 0.0f;

    const float4* __restrict__ W4 = (const float4*)W;
    const float4* __restrict__ x4 = (const float4*)(x + (size_t)row0 * HDIM);

    for (int it = 0; it < (HDIM / 4 / 64); ++it) {
        const int f = it * 64 + lane;               // float4 index in row (0..1023)

        float4 xr[RPW];
#pragma unroll
        for (int r = 0; r < RPW; ++r)
            xr[r] = x4[(size_t)r * (HDIM / 4) + f];  // coalesced 1KB/wave-instr

        // W rows 4f..4f+3 -> 8 contiguous float4 (128B per lane, L2-resident)
        float4 w[8];
#pragma unroll
        for (int j = 0; j < 8; ++j) w[j] = W4[(size_t)f * 8 + j];

#pragma unroll
        for (int r = 0; r < RPW; ++r) {
#pragma unroll
            for (int k = 0; k < 4; ++k) {
                const float xv = (k == 0) ? xr[r].x : (k == 1) ? xr[r].y
                               : (k == 2) ? xr[r].z : xr[r].w;
                const float4 wlo = w[2 * k], whi = w[2 * k + 1];
                acc[r][0] += xv * wlo.x; acc[r][1] += xv * wlo.y;
                acc[r][2] += xv * wlo.z; acc[r][3] += xv * wlo.w;
                acc[r][4] += xv * whi.x; acc[r][5] += xv * whi.y;
                acc[r][6] += xv * whi.z; acc[r][7] += xv * whi.w;
            }
        }
    }

    // ---- butterfly reduce each of the 32 partials across the 64-lane wave ----
#pragma unroll
    for (int r = 0; r < RPW; ++r)
#pragma unroll
        for (int e = 0; e < NE; ++e) {
            float v = acc[r][e];
#pragma unroll
            for (int m = 1; m < 64; m <<= 1) v += __shfl_xor(v, m, 64);
            acc[r][e] = v;   // all lanes now hold the full dot product
        }

    // ---- lanes 0..RPW-1 each own one row: epilogue fully in registers ----
    if (lane < RPW) {
        const int row = row0 + lane;

        float logits[NE];
#pragma unroll
        for (int r = 0; r < RPW; ++r)
            if (lane == r)
#pragma unroll
                for (int e = 0; e < NE; ++e) logits[e] = acc[r][e];

        const float4 b_lo = ((const float4*)bias)[0];
        const float4 b_hi = ((const float4*)bias)[1];
        const float4 n_lo = ((const float4*)(noise + (size_t)row * NE))[0];
        const float4 n_hi = ((const float4*)(noise + (size_t)row * NE))[1];

        logits[0] += b_lo.x + NOISE_EPS * n_lo.x;
        logits[1] += b_lo.y + NOISE_EPS * n_lo.y;
        logits[2] += b_lo.z + NOISE_EPS * n_lo.z;
        logits[3] += b_lo.w + NOISE_EPS * n_lo.w;
        logits[4] += b_hi.x + NOISE_EPS * n_hi.x;
        logits[5] += b_hi.y + NOISE_EPS * n_hi.y;
        logits[6] += b_hi.z + NOISE_EPS * n_hi.z;
        logits[7] += b_hi.w + NOISE_EPS * n_hi.w;

        // softmax (E=8)
        float m = logits[0];
#pragma unroll
        for (int e = 1; e < NE; ++e) m = fmaxf(m, logits[e]);
        float p[NE], s = 0.0f;
#pragma unroll
        for (int e = 0; e < NE; ++e) { p[e] = expf(logits[e] - m); s += p[e]; }
        const float inv_s = 1.0f / s;

        // top-2 (strict > keeps lowest index on ties, matching lax.top_k)
        float v1 = p[0]; int e1 = 0;
#pragma unroll
        for (int e = 1; e < NE; ++e) if (p[e] > v1) { v1 = p[e]; e1 = e; }
        float v2 = -1.0f; int e2 = 0;
#pragma unroll
        for (int e = 0; e < NE; ++e)
            if (e != e1 && p[e] > v2) { v2 = p[e]; e2 = e; }

        const float inv_d = 1.0f / (v1 + v2);
        out[(size_t)row * 2]     = v1 * inv_d;
        out[(size_t)row * 2 + 1] = v2 * inv_d;
        out[(size_t)(BS * 2) + row * 2]     = (float)e1;
        out[(size_t)(BS * 2) + row * 2 + 1] = (float)e2;

        // expert usage (softmax probs, not renormalized) -> block accumulator
#pragma unroll
        for (int e = 0; e < NE; ++e)
            atomicAdd(&block_usage[e], p[e] * inv_s);
    }

    __syncthreads();
    if (tid < NE) atomicAdd(usage_ws + tid, block_usage[tid]);
}

__global__ void router_finalize(const float* __restrict__ usage_ws,
                                float* __restrict__ out) {
    if (threadIdx.x == 0) {
        float aux = 0.0f;
#pragma unroll
        for (int e = 0; e < NE; ++e) {
            const float mean = usage_ws[e] * (1.0f / (float)BS);
            const float d = mean - (1.0f / (float)NE);
            aux += d * d;
        }
        out[(size_t)BS * 4] = LB_COEFF * aux;
    }
}

extern "C" void kernel_launch(void* const* d_in, const int* in_sizes, int n_in,
                              void* d_out, int out_size, void* d_ws, size_t ws_size,
                              hipStream_t stream) {
    const float* x     = (const float*)d_in[0];   // [4,4096,4096]
    const float* W     = (const float*)d_in[1];   // [4096,8]
    const float* b     = (const float*)d_in[2];   // [8]
    const float* noise = (const float*)d_in[3];   // [16384,8]
    float* out = (float*)d_out;
    float* usage = (float*)d_ws;

    hipMemsetAsync(usage, 0, NE * sizeof(float), stream);

    const int groups = BS / RPW;          // 4096 waves
    const int blocks = groups / WPB;      // 1024 blocks of 256 threads
    router_main<<<blocks, 256, 0, stream>>>(x, W, b, noise, out, usage);
    router_finalize<<<1, 64, 0, stream>>>(usage, out);
}

// Round 3
// 371.469 us; speedup vs baseline: 1.1172x; 1.1172x over previous
//
#include <hip/hip_runtime.h>

// NoisyTopKRouter: x[4,4096,4096] f32, W[4096,8] f32, b[8] f32, noise[16384,8] f32
// out: top_k_weights [16384*2] | top_k_indices [16384*2] (as float) | aux_loss [1]
// Memory-bound: stream 256 MiB of x once. Floor ~43 us @ 6.3 TB/s.
//
// Structure: 1 block/CU (1024 thr, 128 KiB LDS). W staged once into LDS with
// XOR swizzle (bank-conflict-free 128B-stride ds_read_b128). Per iter the only
// VMEM is 4x coalesced 1KB x-loads, double-buffered in registers.

#define BS      16384
#define HDIM    4096
#define NE      8
#define RPW     4        // rows per wave
#define NWAVE   16       // waves per block (1024 threads)
#define NITER   (HDIM / 4 / 64)   // 16 float4-chunks per lane per row
#define NOISE_EPS 0.01f
#define LB_COEFF  0.01f

__global__ __launch_bounds__(1024, 4)
void router_main(const float* __restrict__ x, const float* __restrict__ W,
                 const float* __restrict__ bias, const float* __restrict__ noise,
                 float* __restrict__ out, float* __restrict__ usage_ws) {
    const int tid  = threadIdx.x;
    const int lane = tid & 63;
    const int wave = tid >> 6;
    const int row0 = blockIdx.x * (NWAVE * RPW) + wave * RPW;

    // ---- W staged once, swizzled: slot j stored at j^(f&7) within row f ----
    __shared__ float4 w_lds[HDIM * 2];      // 4096 rows * 8 floats = 128 KiB
    __shared__ float block_usage[NE];
    if (tid < NE) block_usage[tid] = 0.0f;
    {
        const float4* __restrict__ W4 = (const float4*)W;
#pragma unroll
        for (int i = tid; i < HDIM * 2; i += 1024) {
            const int f = i >> 3, j = i & 7;
            w_lds[(i & ~7) | (j ^ (f & 7))] = W4[i];
        }
    }
    __syncthreads();

    float acc[RPW][NE];
#pragma unroll
    for (int r = 0; r < RPW; ++r)
#pragma unroll
        for (int e = 0; e < NE; ++e) acc[r][e] = 0.0f;

    const float4* __restrict__ x4 = (const float4*)(x + (size_t)row0 * HDIM);
    const int wxor = lane & 7;              // == f&7 for every iteration

    float4 xa[RPW], xb[RPW];
#pragma unroll
    for (int r = 0; r < RPW; ++r)           // preload iter 0
        xa[r] = x4[(size_t)r * (HDIM / 4) + lane];

#define FMA_HALF(XC, F, KK)                                                   \
    {                                                                         \
        float4 wr[4];                                                         \
        _Pragma("unroll")                                                     \
        for (int m = 0; m < 4; ++m)                                           \
            wr[m] = w_lds[(F) * 8 + ((4 * (KK) + m) ^ wxor)];                 \
        _Pragma("unroll")                                                     \
        for (int r = 0; r < RPW; ++r) {                                       \
            _Pragma("unroll")                                                 \
            for (int kq = 0; kq < 2; ++kq) {                                  \
                const int k = 2 * (KK) + kq;                                  \
                const float xv = ((const float*)&XC[r])[k];                   \
                acc[r][0] += xv * wr[2 * kq].x;                               \
                acc[r][1] += xv * wr[2 * kq].y;                               \
                acc[r][2] += xv * wr[2 * kq].z;                               \
                acc[r][3] += xv * wr[2 * kq].w;                               \
                acc[r][4] += xv * wr[2 * kq + 1].x;                           \
                acc[r][5] += xv * wr[2 * kq + 1].y;                           \
                acc[r][6] += xv * wr[2 * kq + 1].z;                           \
                acc[r][7] += xv * wr[2 * kq + 1].w;                           \
            }                                                                 \
        }                                                                     \
    }

#pragma unroll 1
    for (int it = 0; it < NITER; it += 2) {
        // body A: prefetch it+1 -> xb, compute it from xa
        {
            const int fn = (it + 1) * 64 + lane;
#pragma unroll
            for (int r = 0; r < RPW; ++r)
                xb[r] = x4[(size_t)r * (HDIM / 4) + fn];
            const int f = it * 64 + lane;
            FMA_HALF(xa, f, 0)
            FMA_HALF(xa, f, 1)
        }
        // body B: prefetch it+2 -> xa, compute it+1 from xb
        {
            const int fn = ((it + 2 < NITER) ? (it + 2) : (NITER - 1)) * 64 + lane;
#pragma unroll
            for (int r = 0; r < RPW; ++r)
                xa[r] = x4[(size_t)r * (HDIM / 4) + fn];
            const int f = (it + 1) * 64 + lane;
            FMA_HALF(xb, f, 0)
            FMA_HALF(xb, f, 1)
        }
    }
#undef FMA_HALF

    // ---- butterfly reduce the 32 partials across the 64-lane wave ----
#pragma unroll
    for (int r = 0; r < RPW; ++r)
#pragma unroll
        for (int e = 0; e < NE; ++e) {
            float v = acc[r][e];
#pragma unroll
            for (int m = 1; m < 64; m <<= 1) v += __shfl_xor(v, m, 64);
            acc[r][e] = v;
        }

    // ---- lanes 0..RPW-1 each own one row: epilogue in registers ----
    if (lane < RPW) {
        const int row = row0 + lane;

        float logits[NE];
#pragma unroll
        for (int r = 0; r < RPW; ++r)
            if (lane == r)
#pragma unroll
                for (int e = 0; e < NE; ++e) logits[e] = acc[r][e];

        const float4 b_lo = ((const float4*)bias)[0];
        const float4 b_hi = ((const float4*)bias)[1];
        const float4 n_lo = ((const float4*)(noise + (size_t)row * NE))[0];
        const float4 n_hi = ((const float4*)(noise + (size_t)row * NE))[1];

        logits[0] += b_lo.x + NOISE_EPS * n_lo.x;
        logits[1] += b_lo.y + NOISE_EPS * n_lo.y;
        logits[2] += b_lo.z + NOISE_EPS * n_lo.z;
        logits[3] += b_lo.w + NOISE_EPS * n_lo.w;
        logits[4] += b_hi.x + NOISE_EPS * n_hi.x;
        logits[5] += b_hi.y + NOISE_EPS * n_hi.y;
        logits[6] += b_hi.z + NOISE_EPS * n_hi.z;
        logits[7] += b_hi.w + NOISE_EPS * n_hi.w;

        float m = logits[0];
#pragma unroll
        for (int e = 1; e < NE; ++e) m = fmaxf(m, logits[e]);
        float p[NE], s = 0.0f;
#pragma unroll
        for (int e = 0; e < NE; ++e) { p[e] = expf(logits[e] - m); s += p[e]; }
        const float inv_s = 1.0f / s;

        float v1 = p[0]; int e1 = 0;
#pragma unroll
        for (int e = 1; e < NE; ++e) if (p[e] > v1) { v1 = p[e]; e1 = e; }
        float v2 = -1.0f; int e2 = 0;
#pragma unroll
        for (int e = 0; e < NE; ++e)
            if (e != e1 && p[e] > v2) { v2 = p[e]; e2 = e; }

        const float inv_d = 1.0f / (v1 + v2);
        out[(size_t)row * 2]     = v1 * inv_d;
        out[(size_t)row * 2 + 1] = v2 * inv_d;
        out[(size_t)(BS * 2) + row * 2]     = (float)e1;
        out[(size_t)(BS * 2) + row * 2 + 1] = (float)e2;

#pragma unroll
        for (int e = 0; e < NE; ++e)
            atomicAdd(&block_usage[e], p[e] * inv_s);
    }

    __syncthreads();
    if (tid < NE) atomicAdd(usage_ws + tid, block_usage[tid]);
}

__global__ void router_finalize(const float* __restrict__ usage_ws,
                                float* __restrict__ out) {
    if (threadIdx.x == 0) {
        float aux = 0.0f;
#pragma unroll
        for (int e = 0; e < NE; ++e) {
            const float mean = usage_ws[e] * (1.0f / (float)BS);
            const float d = mean - (1.0f / (float)NE);
            aux += d * d;
        }
        out[(size_t)BS * 4] = LB_COEFF * aux;
    }
}

extern "C" void kernel_launch(void* const* d_in, const int* in_sizes, int n_in,
                              void* d_out, int out_size, void* d_ws, size_t ws_size,
                              hipStream_t stream) {
    const float* x     = (const float*)d_in[0];   // [4,4096,4096]
    const float* W     = (const float*)d_in[1];   // [4096,8]
    const float* b     = (const float*)d_in[2];   // [8]
    const float* noise = (const float*)d_in[3];   // [16384,8]
    float* out = (float*)d_out;
    float* usage = (float*)d_ws;

    hipMemsetAsync(usage, 0, NE * sizeof(float), stream);

    const int blocks = BS / (NWAVE * RPW);        // 256 blocks of 1024 threads
    router_main<<<blocks, 1024, 0, stream>>>(x, W, b, noise, out, usage);
    router_finalize<<<1, 64, 0, stream>>>(usage, out);
}